// Round 14
// baseline (223.402 us; speedup 1.0000x reference)
//
#include <hip/hip_runtime.h>

// ---------------------------------------------------------------------------
// GCNConv + ReLU, aggregate-then-transform (GCN is linear before the GEMM):
//   deg[c]  = 1 + sum_{e: col[e]=c} w[e];  dinv = rsqrt(deg)
//   agg[c]  = dinv[c]^2*x[c] + sum_{e: col[e]=c} (dinv[row]*w*dinv[c]) * x[row]
//   out     = relu(agg @ W + b)
// R9/R10: two-level bucket sort, zero global atomics, dinv folded into xbf2.
// R11: 198us with separate agg(68)/gemm(25). R12 fusion REGRESSED (240us):
//   1563-block fused kernel cut gather TLP 16x (occupancy 70->31%, 3.7->1.5TB/s).
// R12': revert fusion; agg gets TWO-ROW gathers (lane halves process even/odd
//   edges, uint2/lane => 16 rows in flight vs 8) + shfl_xor(32) combine.
//   Keep: wsplit fused into hist's extra block, scan3 folded into consumers.
// ---------------------------------------------------------------------------

#define BSHIFT 6
#define BNODES 64
#define NBS 256          // blocks for hist/scatter

typedef __attribute__((ext_vector_type(8))) short short8v;   // 8 bf16 (4 VGPR)
typedef __attribute__((ext_vector_type(4))) float f32x4;

static __device__ __forceinline__ unsigned short bf16_rne(float f) {
    unsigned int u = __float_as_uint(f);
    u += 0x7FFFu + ((u >> 16) & 1u);
    return (unsigned short)(u >> 16);
}

static __device__ __forceinline__ float bf16f(unsigned short h) {
    return __uint_as_float((unsigned int)h << 16);
}

static __device__ __forceinline__ unsigned int pack_bf2f(float lo, float hi) {
    unsigned int a = __float_as_uint(lo), b = __float_as_uint(hi);
    a = (a + 0x7FFFu + ((a >> 16) & 1u)) >> 16;
    b = (b + 0x7FFFu + ((b >> 16) & 1u)) >> 16;
    return a | (b << 16);
}

static __device__ __forceinline__ float2 bf2_to_f2(unsigned int u) {
    union { unsigned int i; float f; } a, b;
    a.i = u << 16;
    b.i = u & 0xFFFF0000u;
    return make_float2(a.f, b.f);
}

// xbf2[node] = bf16(x[node] * dinv[node]), packed pairs.
__global__ void cvt_kernel(const float* __restrict__ x, const float* __restrict__ dinv,
                           unsigned int* __restrict__ xbf2, int nx8) {
    int stride = gridDim.x * blockDim.x;
    for (int t = blockIdx.x * blockDim.x + threadIdx.x; t < nx8; t += stride) {
        float di = dinv[t >> 4];
        const float4* xin = reinterpret_cast<const float4*>(x);
        float4 a = xin[t * 2];
        float4 b = xin[t * 2 + 1];
        uint4 o;
        o.x = pack_bf2f(a.x * di, a.y * di);
        o.y = pack_bf2f(a.z * di, a.w * di);
        o.z = pack_bf2f(b.x * di, b.y * di);
        o.w = pack_bf2f(b.z * di, b.w * di);
        reinterpret_cast<uint4*>(xbf2)[t] = o;
    }
}

// Per-block LDS histogram -> histM[bin][blk] (no atomics).
// Extra block does the W hi/lo transpose-split (fused wsplit).
__launch_bounds__(1024)
__global__ void coarse_hist(const int* __restrict__ col,
                            unsigned int* __restrict__ histM,
                            const float* __restrict__ W,
                            unsigned short* __restrict__ Whi,
                            unsigned short* __restrict__ Wlo,
                            int E, int epb, int nb) {
    if (blockIdx.x == NBS) {   // fused wsplit
        for (int t = threadIdx.x; t < 128 * 128; t += 1024) {
            int k = t >> 7;
            int c = t & 127;
            float v = W[k * 128 + c];
            unsigned short h = bf16_rne(v);
            unsigned short l = bf16_rne(v - bf16f(h));
            Whi[c * 128 + k] = h;
            Wlo[c * 128 + k] = l;
        }
        return;
    }
    extern __shared__ unsigned int lh[];
    for (int i = threadIdx.x; i < nb; i += blockDim.x) lh[i] = 0;
    __syncthreads();
    int s = blockIdx.x * epb;
    int e = s + epb; if (e > E) e = E;
    for (int i = s + threadIdx.x; i < e; i += blockDim.x)
        atomicAdd(&lh[((unsigned)col[i]) >> BSHIFT], 1u);
    __syncthreads();
    for (int i = threadIdx.x; i < nb; i += blockDim.x)
        histM[(size_t)i * NBS + blockIdx.x] = lh[i];
}

// Hierarchical exclusive scan over histM (M = nb*NBS), in place; consumers
// add bsums[idx>>10] themselves.
__launch_bounds__(256)
__global__ void scan1i(unsigned int* __restrict__ data,
                       unsigned int* __restrict__ bsums, int M) {
    __shared__ unsigned int wsum[4];
    const int tid = threadIdx.x;
    const int lane = tid & 63, wv = tid >> 6;
    const int base = blockIdx.x * 1024 + tid * 4;

    unsigned c0 = 0, c1 = 0, c2 = 0, c3 = 0;
    if (base + 3 < M) {
        uint4 c = *reinterpret_cast<const uint4*>(&data[base]);
        c0 = c.x; c1 = c.y; c2 = c.z; c3 = c.w;
    } else {
        if (base     < M) c0 = data[base];
        if (base + 1 < M) c1 = data[base + 1];
        if (base + 2 < M) c2 = data[base + 2];
    }
    unsigned s1 = c0 + c1, s2 = s1 + c2, s3 = s2 + c3;
    unsigned incl = s3;
    #pragma unroll
    for (int off = 1; off < 64; off <<= 1) {
        unsigned v = __shfl_up(incl, off);
        if (lane >= off) incl += v;
    }
    if (lane == 63) wsum[wv] = incl;
    __syncthreads();
    if (tid == 0) {
        unsigned a = 0;
        #pragma unroll
        for (int i = 0; i < 4; ++i) { unsigned t = wsum[i]; wsum[i] = a; a += t; }
        bsums[blockIdx.x] = a;
    }
    __syncthreads();
    unsigned ex = wsum[wv] + (incl - s3);
    if (base + 3 < M) {
        uint4 o; o.x = ex; o.y = ex + c0; o.z = ex + s1; o.w = ex + s2;
        *reinterpret_cast<uint4*>(&data[base]) = o;
    } else {
        if (base     < M) data[base]     = ex;
        if (base + 1 < M) data[base + 1] = ex + c0;
        if (base + 2 < M) data[base + 2] = ex + s1;
    }
}

__global__ void scan2(unsigned int* __restrict__ bsums, int nbq) {
    __shared__ unsigned int lds[1024];
    int tid = threadIdx.x;
    if (tid < nbq) lds[tid] = bsums[tid];
    __syncthreads();
    if (tid == 0) {
        unsigned a = 0;
        for (int i = 0; i < nbq; ++i) { unsigned t = lds[i]; lds[i] = a; a += t; }
    }
    __syncthreads();
    if (tid < nbq) bsums[tid] = lds[tid];
}

// Group edges by coarse bucket; bases from scanned histM + bsums fixup.
__launch_bounds__(1024)
__global__ void bucket_scatter(const int* __restrict__ row, const int* __restrict__ col,
                               const float* __restrict__ w,
                               const unsigned int* __restrict__ histM,
                               const unsigned int* __restrict__ bsums,
                               int2* __restrict__ bucketed, int E, int epb, int nb) {
    extern __shared__ unsigned int lds[];
    unsigned int* lbase = lds;
    unsigned int* lpos = lds + nb;
    for (int i = threadIdx.x; i < nb; i += blockDim.x) {
        size_t idx = (size_t)i * NBS + blockIdx.x;
        lbase[i] = histM[idx] + bsums[idx >> 10];
        lpos[i] = 0;
    }
    __syncthreads();
    int s = blockIdx.x * epb;
    int e = s + epb; if (e > E) e = E;
    for (int i = s + threadIdx.x; i < e; i += blockDim.x) {
        int c = col[i];
        int bk = ((unsigned)c) >> BSHIFT;
        unsigned p = lbase[bk] + atomicAdd(&lpos[bk], 1u);
        bucketed[p] = make_int2(row[i] | ((c & (BNODES - 1)) << 24),
                                __float_as_int(w[i]));
    }
}

// One block per bucket: LDS count+weighted-degree, dinv/offs, csr placement.
__launch_bounds__(256)
__global__ void bucket_finalize(const int2* __restrict__ bucketed,
                                const unsigned int* __restrict__ histM,
                                const unsigned int* __restrict__ bsums,
                                float* __restrict__ dinv, int* __restrict__ offs,
                                int2* __restrict__ csr, int n, int E, int nb) {
    __shared__ unsigned long long pdeg[BNODES];
    __shared__ unsigned int fineEx[BNODES];
    __shared__ unsigned int lcur[BNODES];
    const int b = blockIdx.x, tid = threadIdx.x;
    const int node0 = b << BSHIFT;
    const int nNodes = min(BNODES, n - node0);
    size_t si = (size_t)b * NBS;
    const unsigned s = histM[si] + bsums[si >> 10];
    unsigned e;
    if (b + 1 < nb) {
        size_t ei = (size_t)(b + 1) * NBS;
        e = histM[ei] + bsums[ei >> 10];
    } else {
        e = (unsigned)E;
    }

    if (tid < BNODES) { pdeg[tid] = (1ull << 24); lcur[tid] = 0; }  // deg=1 (self-loop)
    __syncthreads();
    for (unsigned i = s + tid; i < e; i += 256) {
        int2 m = bucketed[i];
        unsigned cl = ((unsigned)m.x) >> 24;
        unsigned fx = (unsigned)(__int_as_float(m.y) * 16777216.0f);
        atomicAdd(&pdeg[cl], (1ull << 32) | (unsigned long long)fx);
    }
    __syncthreads();
    if (tid < BNODES) {   // wave 0 only: 64-lane scan
        unsigned long long p = pdeg[tid];
        unsigned cnt = (unsigned)(p >> 32);
        unsigned incl = cnt;
        #pragma unroll
        for (int off = 1; off < 64; off <<= 1) {
            unsigned v = __shfl_up(incl, off);
            if (tid >= off) incl += v;
        }
        fineEx[tid] = incl - cnt;
        if (tid < nNodes) {
            dinv[node0 + tid] = rsqrtf((float)(unsigned)p * 5.9604644775390625e-8f);
            offs[node0 + tid] = (int)(s + incl - cnt);
        }
    }
    __syncthreads();
    for (unsigned i = s + tid; i < e; i += 256) {
        int2 m = bucketed[i];
        unsigned cl = ((unsigned)m.x) >> 24;
        int r = m.x & 0x00FFFFFF;
        unsigned pos = s + fineEx[cl] + atomicAdd(&lcur[cl], 1u);
        csr[pos] = make_int2(r, m.y);   // (srcRow, w bits)
    }
    if (b == 0 && tid == 0) offs[n] = E;
}

// One wave per node; lane halves process even/odd edges so one gather
// instruction fetches TWO 256B rows -> 16 rows in flight per wave.
// Lane l: half = l>>5, sl = l&31 owns channels [4sl, 4sl+4).
__launch_bounds__(256)
__global__ void agg_kernel_bf16(const unsigned int* __restrict__ xbf2,
                                const float* __restrict__ dinv,
                                const int* __restrict__ offs, const int2* __restrict__ csr,
                                float* __restrict__ aggOut, int n) {
    int wid = (blockIdx.x * blockDim.x + threadIdx.x) >> 6;
    int l = threadIdx.x & 63;
    if (wid >= n) return;
    const int half = l >> 5;
    const int sl = l & 31;

    float di = dinv[wid];
    float4 acc = make_float4(0.f, 0.f, 0.f, 0.f);
    if (half == 0) {   // self term once: di^2 * x = di * (x*dinv)
        uint2 xi = *reinterpret_cast<const uint2*>(&xbf2[(size_t)wid * 64 + 2 * sl]);
        float2 a = bf2_to_f2(xi.x), b = bf2_to_f2(xi.y);
        acc.x = di * a.x; acc.y = di * a.y; acc.z = di * b.x; acc.w = di * b.y;
    }

    int s = offs[wid];
    int e = offs[wid + 1];
    int j = s;

    // 8 pair-iterations = 16 edges; this half handles 8 of them.
    for (; j + 16 <= e; j += 16) {
        int2 m0 = csr[j + 0 + half];  int2 m1 = csr[j + 2 + half];
        int2 m2 = csr[j + 4 + half];  int2 m3 = csr[j + 6 + half];
        int2 m4 = csr[j + 8 + half];  int2 m5 = csr[j + 10 + half];
        int2 m6 = csr[j + 12 + half]; int2 m7 = csr[j + 14 + half];
        uint2 v0 = *reinterpret_cast<const uint2*>(&xbf2[(size_t)m0.x * 64 + 2 * sl]);
        uint2 v1 = *reinterpret_cast<const uint2*>(&xbf2[(size_t)m1.x * 64 + 2 * sl]);
        uint2 v2 = *reinterpret_cast<const uint2*>(&xbf2[(size_t)m2.x * 64 + 2 * sl]);
        uint2 v3 = *reinterpret_cast<const uint2*>(&xbf2[(size_t)m3.x * 64 + 2 * sl]);
        uint2 v4 = *reinterpret_cast<const uint2*>(&xbf2[(size_t)m4.x * 64 + 2 * sl]);
        uint2 v5 = *reinterpret_cast<const uint2*>(&xbf2[(size_t)m5.x * 64 + 2 * sl]);
        uint2 v6 = *reinterpret_cast<const uint2*>(&xbf2[(size_t)m6.x * 64 + 2 * sl]);
        uint2 v7 = *reinterpret_cast<const uint2*>(&xbf2[(size_t)m7.x * 64 + 2 * sl]);
        float w0 = __int_as_float(m0.y) * di; float w1 = __int_as_float(m1.y) * di;
        float w2 = __int_as_float(m2.y) * di; float w3 = __int_as_float(m3.y) * di;
        float w4 = __int_as_float(m4.y) * di; float w5 = __int_as_float(m5.y) * di;
        float w6 = __int_as_float(m6.y) * di; float w7 = __int_as_float(m7.y) * di;
        float2 a, b;
        a = bf2_to_f2(v0.x); b = bf2_to_f2(v0.y);
        acc.x += w0 * a.x; acc.y += w0 * a.y; acc.z += w0 * b.x; acc.w += w0 * b.y;
        a = bf2_to_f2(v1.x); b = bf2_to_f2(v1.y);
        acc.x += w1 * a.x; acc.y += w1 * a.y; acc.z += w1 * b.x; acc.w += w1 * b.y;
        a = bf2_to_f2(v2.x); b = bf2_to_f2(v2.y);
        acc.x += w2 * a.x; acc.y += w2 * a.y; acc.z += w2 * b.x; acc.w += w2 * b.y;
        a = bf2_to_f2(v3.x); b = bf2_to_f2(v3.y);
        acc.x += w3 * a.x; acc.y += w3 * a.y; acc.z += w3 * b.x; acc.w += w3 * b.y;
        a = bf2_to_f2(v4.x); b = bf2_to_f2(v4.y);
        acc.x += w4 * a.x; acc.y += w4 * a.y; acc.z += w4 * b.x; acc.w += w4 * b.y;
        a = bf2_to_f2(v5.x); b = bf2_to_f2(v5.y);
        acc.x += w5 * a.x; acc.y += w5 * a.y; acc.z += w5 * b.x; acc.w += w5 * b.y;
        a = bf2_to_f2(v6.x); b = bf2_to_f2(v6.y);
        acc.x += w6 * a.x; acc.y += w6 * a.y; acc.z += w6 * b.x; acc.w += w6 * b.y;
        a = bf2_to_f2(v7.x); b = bf2_to_f2(v7.y);
        acc.x += w7 * a.x; acc.y += w7 * a.y; acc.z += w7 * b.x; acc.w += w7 * b.y;
    }
    // pairwise remainder
    for (; j + 2 <= e; j += 2) {
        int2 m = csr[j + half];
        uint2 v = *reinterpret_cast<const uint2*>(&xbf2[(size_t)m.x * 64 + 2 * sl]);
        float wn = __int_as_float(m.y) * di;
        float2 a = bf2_to_f2(v.x), b = bf2_to_f2(v.y);
        acc.x += wn * a.x; acc.y += wn * a.y; acc.z += wn * b.x; acc.w += wn * b.y;
    }
    // odd final edge: half 0 only
    if (j < e && half == 0) {
        int2 m = csr[j];
        uint2 v = *reinterpret_cast<const uint2*>(&xbf2[(size_t)m.x * 64 + 2 * sl]);
        float wn = __int_as_float(m.y) * di;
        float2 a = bf2_to_f2(v.x), b = bf2_to_f2(v.y);
        acc.x += wn * a.x; acc.y += wn * a.y; acc.z += wn * b.x; acc.w += wn * b.y;
    }

    // combine halves (lane l <-> l^32 hold same channels, different edge parity)
    acc.x += __shfl_xor(acc.x, 32);
    acc.y += __shfl_xor(acc.y, 32);
    acc.z += __shfl_xor(acc.z, 32);
    acc.w += __shfl_xor(acc.w, 32);
    if (half == 0)
        *reinterpret_cast<float4*>(&aggOut[(size_t)wid * 128 + 4 * sl]) = acc;
}

// MFMA GEMM, in-place on io: io = relu(io @ W + b), bf16x3, no LDS.
__launch_bounds__(256)
__global__ void gemm_mfma2(const unsigned short* __restrict__ Whi,
                           const unsigned short* __restrict__ Wlo,
                           const float* __restrict__ bias,
                           float* __restrict__ io, int n) {
    const int tid = threadIdx.x;
    const int wv = tid >> 6;
    const int l = tid & 63;
    const int row0 = (blockIdx.x * 4 + wv) * 16;
    if (row0 >= n) return;

    const int arow = row0 + (l & 15);
    const int koff = (l >> 4) * 8;
    const bool rok = arow < n;

    short8v ahi[4], alo[4];
    #pragma unroll
    for (int kc = 0; kc < 4; ++kc) {
        float4 p0 = make_float4(0.f, 0.f, 0.f, 0.f);
        float4 p1 = p0;
        if (rok) {
            const float* src = io + (size_t)arow * 128 + kc * 32 + koff;
            p0 = *reinterpret_cast<const float4*>(src);
            p1 = *reinterpret_cast<const float4*>(src + 4);
        }
        float a8[8] = {p0.x, p0.y, p0.z, p0.w, p1.x, p1.y, p1.z, p1.w};
        #pragma unroll
        for (int j = 0; j < 8; ++j) {
            unsigned short h = bf16_rne(a8[j]);
            ahi[kc][j] = (short)h;
            alo[kc][j] = (short)bf16_rne(a8[j] - bf16f(h));
        }
    }

    const int orow = row0 + (l >> 4) * 4;
    const int cbase = l & 15;
    #pragma unroll
    for (int cf = 0; cf < 8; ++cf) {
        int c = cf * 16 + cbase;
        const unsigned short* ph = Whi + c * 128 + koff;
        const unsigned short* pl = Wlo + c * 128 + koff;
        f32x4 acc = {0.f, 0.f, 0.f, 0.f};
        #pragma unroll
        for (int kc = 0; kc < 4; ++kc) {
            short8v bh = *reinterpret_cast<const short8v*>(ph + kc * 32);
            short8v bl = *reinterpret_cast<const short8v*>(pl + kc * 32);
            acc = __builtin_amdgcn_mfma_f32_16x16x32_bf16(ahi[kc], bh, acc, 0, 0, 0);
            acc = __builtin_amdgcn_mfma_f32_16x16x32_bf16(ahi[kc], bl, acc, 0, 0, 0);
            acc = __builtin_amdgcn_mfma_f32_16x16x32_bf16(alo[kc], bh, acc, 0, 0, 0);
        }
        float bb = bias[c];
        #pragma unroll
        for (int j = 0; j < 4; ++j) {
            int r = orow + j;
            if (r < n) io[(size_t)r * 128 + c] = fmaxf(acc[j] + bb, 0.f);
        }
    }
}

static inline size_t align256(size_t v) { return (v + 255) & ~(size_t)255; }

extern "C" void kernel_launch(void* const* d_in, const int* in_sizes, int n_in,
                              void* d_out, int out_size, void* d_ws, size_t ws_size,
                              hipStream_t stream) {
    const float* x = (const float*)d_in[0];
    const int* ei = (const int*)d_in[1];        // harness: integer -> int32
    const float* w = (const float*)d_in[2];
    const float* W = (const float*)d_in[3];
    const float* b = (const float*)d_in[4];
    float* out = (float*)d_out;

    const int N = in_sizes[0] / 128;
    const int E = in_sizes[2];
    const int* row = ei;       // source
    const int* col = ei + E;   // target

    const int nb = (N + BNODES - 1) / BNODES;   // 1563 coarse buckets
    const int M = nb * NBS;                     // histM elements (~400k)
    const int nScanB = (M + 1023) / 1024;       // 391

    // Workspace (~39.3 MB):
    // [dinv][offs][Whi][Wlo][csr][ UNION: (histM|bsums|bucketed)  vs  xbf2 ]
    char* base = (char*)d_ws;
    size_t off = 0;
    float* dinv = (float*)(base + off);          off = align256(off + (size_t)N * 4);
    int* offs = (int*)(base + off);              off = align256(off + ((size_t)N + 1) * 4);
    unsigned short* Whi = (unsigned short*)(base + off);
    off = align256(off + (size_t)128 * 128 * 2);
    unsigned short* Wlo = (unsigned short*)(base + off);
    off = align256(off + (size_t)128 * 128 * 2);
    int2* csr = (int2*)(base + off);             off = align256(off + (size_t)E * 8);
    // union region
    char* uni = base + off;
    unsigned int* histM = (unsigned int*)uni;                      // M*4 = 1.6 MB
    size_t uoff = align256((size_t)M * 4);
    unsigned int* bsums = (unsigned int*)(uni + uoff);
    uoff = align256(uoff + (size_t)nScanB * 4);
    int2* bucketed = (int2*)(uni + uoff);                          // E*8 = 12.8 MB
    unsigned int* xbf2 = (unsigned int*)uni;                       // N*256 = 25.6 MB

    const int epb = (E + NBS - 1) / NBS;       // 6250
    const int nx8 = (N * 128) / 8;

    // 1: hist (+fused wsplit in the extra block)
    coarse_hist<<<NBS + 1, 1024, nb * 4, stream>>>(col, histM, W, Whi, Wlo, E, epb, nb);
    // 2-3: scan
    scan1i<<<nScanB, 256, 0, stream>>>(histM, bsums, M);
    scan2<<<1, 1024, 0, stream>>>(bsums, nScanB);
    // 4: bucket the edges (zero global atomics)
    bucket_scatter<<<NBS, 1024, 2 * nb * 4, stream>>>(row, col, w, histM, bsums,
                                                      bucketed, E, epb, nb);
    // 5: per-bucket degree + csr placement
    bucket_finalize<<<nb, 256, 0, stream>>>(bucketed, histM, bsums, dinv, offs,
                                            csr, N, E, nb);
    // 6: x*dinv -> bf16 (overwrites union; bucketed is dead)
    cvt_kernel<<<2048, 256, 0, stream>>>(x, dinv, xbf2, nx8);
    // 7: aggregate (two-row gathers, 16 rows in flight/wave) -> d_out fp32
    agg_kernel_bf16<<<(N + 3) / 4, 256, 0, stream>>>(xbf2, dinv, offs, csr, out, N);
    // 8: out = relu(out @ W + b), in-place MFMA
    gemm_mfma2<<<(N + 63) / 64, 256, 0, stream>>>(Whi, Wlo, b, out, N);
}

// Round 15
// 210.343 us; speedup vs baseline: 1.0621x; 1.0621x over previous
//
#include <hip/hip_runtime.h>

// ---------------------------------------------------------------------------
// GCNConv + ReLU, aggregate-then-transform (GCN is linear before the GEMM):
//   deg[c]  = 1 + sum_{e: col[e]=c} w[e];  dinv = rsqrt(deg)
//   agg[c]  = dinv[c]^2*x[c] + sum_{e: col[e]=c} (dinv[row]*w*dinv[c]) * x[row]
//   out     = relu(agg @ W + b)
// R9/R10: two-level bucket sort, zero global atomics, dinv folded into xbf2.
// R11: separate agg(68us)/gemm(25us) = 198us total.
// R12 fusion REGRESSED (240us): killed gather TLP. R14 two-row gathers
// REGRESSED (agg 68->81us): wider loads cut independent row-streams per
// vmem slot; service rate fell 3.7->2.5 TB/s.
// R14': agg reverted to R11's one-dword-per-lane 8-deep loop (empirical best;
//   ~6 TB/s logical gather rate = at the random-gather service wall).
//   Kept: wsplit fused into hist's extra block, scan3 folded into consumers.
// ---------------------------------------------------------------------------

#define BSHIFT 6
#define BNODES 64
#define NBS 256          // blocks for hist/scatter

typedef __attribute__((ext_vector_type(8))) short short8v;   // 8 bf16 (4 VGPR)
typedef __attribute__((ext_vector_type(4))) float f32x4;

static __device__ __forceinline__ unsigned short bf16_rne(float f) {
    unsigned int u = __float_as_uint(f);
    u += 0x7FFFu + ((u >> 16) & 1u);
    return (unsigned short)(u >> 16);
}

static __device__ __forceinline__ float bf16f(unsigned short h) {
    return __uint_as_float((unsigned int)h << 16);
}

static __device__ __forceinline__ unsigned int pack_bf2f(float lo, float hi) {
    unsigned int a = __float_as_uint(lo), b = __float_as_uint(hi);
    a = (a + 0x7FFFu + ((a >> 16) & 1u)) >> 16;
    b = (b + 0x7FFFu + ((b >> 16) & 1u)) >> 16;
    return a | (b << 16);
}

static __device__ __forceinline__ float2 bf2_to_f2(unsigned int u) {
    union { unsigned int i; float f; } a, b;
    a.i = u << 16;
    b.i = u & 0xFFFF0000u;
    return make_float2(a.f, b.f);
}

// xbf2[node] = bf16(x[node] * dinv[node]), packed pairs.
__global__ void cvt_kernel(const float* __restrict__ x, const float* __restrict__ dinv,
                           unsigned int* __restrict__ xbf2, int nx8) {
    int stride = gridDim.x * blockDim.x;
    for (int t = blockIdx.x * blockDim.x + threadIdx.x; t < nx8; t += stride) {
        float di = dinv[t >> 4];
        const float4* xin = reinterpret_cast<const float4*>(x);
        float4 a = xin[t * 2];
        float4 b = xin[t * 2 + 1];
        uint4 o;
        o.x = pack_bf2f(a.x * di, a.y * di);
        o.y = pack_bf2f(a.z * di, a.w * di);
        o.z = pack_bf2f(b.x * di, b.y * di);
        o.w = pack_bf2f(b.z * di, b.w * di);
        reinterpret_cast<uint4*>(xbf2)[t] = o;
    }
}

// Per-block LDS histogram -> histM[bin][blk] (no atomics).
// Extra block does the W hi/lo transpose-split (fused wsplit).
__launch_bounds__(1024)
__global__ void coarse_hist(const int* __restrict__ col,
                            unsigned int* __restrict__ histM,
                            const float* __restrict__ W,
                            unsigned short* __restrict__ Whi,
                            unsigned short* __restrict__ Wlo,
                            int E, int epb, int nb) {
    if (blockIdx.x == NBS) {   // fused wsplit
        for (int t = threadIdx.x; t < 128 * 128; t += 1024) {
            int k = t >> 7;
            int c = t & 127;
            float v = W[k * 128 + c];
            unsigned short h = bf16_rne(v);
            unsigned short l = bf16_rne(v - bf16f(h));
            Whi[c * 128 + k] = h;
            Wlo[c * 128 + k] = l;
        }
        return;
    }
    extern __shared__ unsigned int lh[];
    for (int i = threadIdx.x; i < nb; i += blockDim.x) lh[i] = 0;
    __syncthreads();
    int s = blockIdx.x * epb;
    int e = s + epb; if (e > E) e = E;
    for (int i = s + threadIdx.x; i < e; i += blockDim.x)
        atomicAdd(&lh[((unsigned)col[i]) >> BSHIFT], 1u);
    __syncthreads();
    for (int i = threadIdx.x; i < nb; i += blockDim.x)
        histM[(size_t)i * NBS + blockIdx.x] = lh[i];
}

// Hierarchical exclusive scan over histM (M = nb*NBS), in place; consumers
// add bsums[idx>>10] themselves.
__launch_bounds__(256)
__global__ void scan1i(unsigned int* __restrict__ data,
                       unsigned int* __restrict__ bsums, int M) {
    __shared__ unsigned int wsum[4];
    const int tid = threadIdx.x;
    const int lane = tid & 63, wv = tid >> 6;
    const int base = blockIdx.x * 1024 + tid * 4;

    unsigned c0 = 0, c1 = 0, c2 = 0, c3 = 0;
    if (base + 3 < M) {
        uint4 c = *reinterpret_cast<const uint4*>(&data[base]);
        c0 = c.x; c1 = c.y; c2 = c.z; c3 = c.w;
    } else {
        if (base     < M) c0 = data[base];
        if (base + 1 < M) c1 = data[base + 1];
        if (base + 2 < M) c2 = data[base + 2];
    }
    unsigned s1 = c0 + c1, s2 = s1 + c2, s3 = s2 + c3;
    unsigned incl = s3;
    #pragma unroll
    for (int off = 1; off < 64; off <<= 1) {
        unsigned v = __shfl_up(incl, off);
        if (lane >= off) incl += v;
    }
    if (lane == 63) wsum[wv] = incl;
    __syncthreads();
    if (tid == 0) {
        unsigned a = 0;
        #pragma unroll
        for (int i = 0; i < 4; ++i) { unsigned t = wsum[i]; wsum[i] = a; a += t; }
        bsums[blockIdx.x] = a;
    }
    __syncthreads();
    unsigned ex = wsum[wv] + (incl - s3);
    if (base + 3 < M) {
        uint4 o; o.x = ex; o.y = ex + c0; o.z = ex + s1; o.w = ex + s2;
        *reinterpret_cast<uint4*>(&data[base]) = o;
    } else {
        if (base     < M) data[base]     = ex;
        if (base + 1 < M) data[base + 1] = ex + c0;
        if (base + 2 < M) data[base + 2] = ex + s1;
    }
}

__global__ void scan2(unsigned int* __restrict__ bsums, int nbq) {
    __shared__ unsigned int lds[1024];
    int tid = threadIdx.x;
    if (tid < nbq) lds[tid] = bsums[tid];
    __syncthreads();
    if (tid == 0) {
        unsigned a = 0;
        for (int i = 0; i < nbq; ++i) { unsigned t = lds[i]; lds[i] = a; a += t; }
    }
    __syncthreads();
    if (tid < nbq) bsums[tid] = lds[tid];
}

// Group edges by coarse bucket; bases from scanned histM + bsums fixup.
__launch_bounds__(1024)
__global__ void bucket_scatter(const int* __restrict__ row, const int* __restrict__ col,
                               const float* __restrict__ w,
                               const unsigned int* __restrict__ histM,
                               const unsigned int* __restrict__ bsums,
                               int2* __restrict__ bucketed, int E, int epb, int nb) {
    extern __shared__ unsigned int lds[];
    unsigned int* lbase = lds;
    unsigned int* lpos = lds + nb;
    for (int i = threadIdx.x; i < nb; i += blockDim.x) {
        size_t idx = (size_t)i * NBS + blockIdx.x;
        lbase[i] = histM[idx] + bsums[idx >> 10];
        lpos[i] = 0;
    }
    __syncthreads();
    int s = blockIdx.x * epb;
    int e = s + epb; if (e > E) e = E;
    for (int i = s + threadIdx.x; i < e; i += blockDim.x) {
        int c = col[i];
        int bk = ((unsigned)c) >> BSHIFT;
        unsigned p = lbase[bk] + atomicAdd(&lpos[bk], 1u);
        bucketed[p] = make_int2(row[i] | ((c & (BNODES - 1)) << 24),
                                __float_as_int(w[i]));
    }
}

// One block per bucket: LDS count+weighted-degree, dinv/offs, csr placement.
__launch_bounds__(256)
__global__ void bucket_finalize(const int2* __restrict__ bucketed,
                                const unsigned int* __restrict__ histM,
                                const unsigned int* __restrict__ bsums,
                                float* __restrict__ dinv, int* __restrict__ offs,
                                int2* __restrict__ csr, int n, int E, int nb) {
    __shared__ unsigned long long pdeg[BNODES];
    __shared__ unsigned int fineEx[BNODES];
    __shared__ unsigned int lcur[BNODES];
    const int b = blockIdx.x, tid = threadIdx.x;
    const int node0 = b << BSHIFT;
    const int nNodes = min(BNODES, n - node0);
    size_t si = (size_t)b * NBS;
    const unsigned s = histM[si] + bsums[si >> 10];
    unsigned e;
    if (b + 1 < nb) {
        size_t ei = (size_t)(b + 1) * NBS;
        e = histM[ei] + bsums[ei >> 10];
    } else {
        e = (unsigned)E;
    }

    if (tid < BNODES) { pdeg[tid] = (1ull << 24); lcur[tid] = 0; }  // deg=1 (self-loop)
    __syncthreads();
    for (unsigned i = s + tid; i < e; i += 256) {
        int2 m = bucketed[i];
        unsigned cl = ((unsigned)m.x) >> 24;
        unsigned fx = (unsigned)(__int_as_float(m.y) * 16777216.0f);
        atomicAdd(&pdeg[cl], (1ull << 32) | (unsigned long long)fx);
    }
    __syncthreads();
    if (tid < BNODES) {   // wave 0 only: 64-lane scan
        unsigned long long p = pdeg[tid];
        unsigned cnt = (unsigned)(p >> 32);
        unsigned incl = cnt;
        #pragma unroll
        for (int off = 1; off < 64; off <<= 1) {
            unsigned v = __shfl_up(incl, off);
            if (tid >= off) incl += v;
        }
        fineEx[tid] = incl - cnt;
        if (tid < nNodes) {
            dinv[node0 + tid] = rsqrtf((float)(unsigned)p * 5.9604644775390625e-8f);
            offs[node0 + tid] = (int)(s + incl - cnt);
        }
    }
    __syncthreads();
    for (unsigned i = s + tid; i < e; i += 256) {
        int2 m = bucketed[i];
        unsigned cl = ((unsigned)m.x) >> 24;
        int r = m.x & 0x00FFFFFF;
        unsigned pos = s + fineEx[cl] + atomicAdd(&lcur[cl], 1u);
        csr[pos] = make_int2(r, m.y);   // (srcRow, w bits)
    }
    if (b == 0 && tid == 0) offs[n] = E;
}

// One wave per node, bf16 gathers, 8-way ILP (R11 structure — empirical best).
// xbf2 rows pre-scaled by dinv[r]; per-edge weight = w * dinv[dest].
__launch_bounds__(256)
__global__ void agg_kernel_bf16(const unsigned int* __restrict__ xbf2,
                                const float* __restrict__ dinv,
                                const int* __restrict__ offs, const int2* __restrict__ csr,
                                float* __restrict__ aggOut, int n) {
    int wid = (blockIdx.x * blockDim.x + threadIdx.x) >> 6;
    int lane = threadIdx.x & 63;
    if (wid >= n) return;

    float di = dinv[wid];
    float2 xi = bf2_to_f2(xbf2[(size_t)wid * 64 + lane]);   // = x*dinv already
    float ax0 = di * xi.x, ay0 = di * xi.y;                 // self: di^2 * x
    float ax1 = 0.f,       ay1 = 0.f;

    int s = offs[wid];
    int e = offs[wid + 1];
    int j = s;

    for (; j + 8 <= e; j += 8) {
        int2 m0 = csr[j + 0]; int2 m1 = csr[j + 1];
        int2 m2 = csr[j + 2]; int2 m3 = csr[j + 3];
        int2 m4 = csr[j + 4]; int2 m5 = csr[j + 5];
        int2 m6 = csr[j + 6]; int2 m7 = csr[j + 7];
        unsigned int v0 = xbf2[(size_t)m0.x * 64 + lane];
        unsigned int v1 = xbf2[(size_t)m1.x * 64 + lane];
        unsigned int v2 = xbf2[(size_t)m2.x * 64 + lane];
        unsigned int v3 = xbf2[(size_t)m3.x * 64 + lane];
        unsigned int v4 = xbf2[(size_t)m4.x * 64 + lane];
        unsigned int v5 = xbf2[(size_t)m5.x * 64 + lane];
        unsigned int v6 = xbf2[(size_t)m6.x * 64 + lane];
        unsigned int v7 = xbf2[(size_t)m7.x * 64 + lane];
        float2 f0 = bf2_to_f2(v0); float2 f1 = bf2_to_f2(v1);
        float2 f2 = bf2_to_f2(v2); float2 f3 = bf2_to_f2(v3);
        float2 f4 = bf2_to_f2(v4); float2 f5 = bf2_to_f2(v5);
        float2 f6 = bf2_to_f2(v6); float2 f7 = bf2_to_f2(v7);
        float w0 = __int_as_float(m0.y) * di; float w1 = __int_as_float(m1.y) * di;
        float w2 = __int_as_float(m2.y) * di; float w3 = __int_as_float(m3.y) * di;
        float w4 = __int_as_float(m4.y) * di; float w5 = __int_as_float(m5.y) * di;
        float w6 = __int_as_float(m6.y) * di; float w7 = __int_as_float(m7.y) * di;
        ax0 += w0 * f0.x; ay0 += w0 * f0.y;
        ax1 += w1 * f1.x; ay1 += w1 * f1.y;
        ax0 += w2 * f2.x; ay0 += w2 * f2.y;
        ax1 += w3 * f3.x; ay1 += w3 * f3.y;
        ax0 += w4 * f4.x; ay0 += w4 * f4.y;
        ax1 += w5 * f5.x; ay1 += w5 * f5.y;
        ax0 += w6 * f6.x; ay0 += w6 * f6.y;
        ax1 += w7 * f7.x; ay1 += w7 * f7.y;
    }
    for (; j + 2 <= e; j += 2) {
        int2 m0 = csr[j + 0]; int2 m1 = csr[j + 1];
        unsigned int v0 = xbf2[(size_t)m0.x * 64 + lane];
        unsigned int v1 = xbf2[(size_t)m1.x * 64 + lane];
        float w0 = __int_as_float(m0.y) * di;
        float w1 = __int_as_float(m1.y) * di;
        float2 f0 = bf2_to_f2(v0); float2 f1 = bf2_to_f2(v1);
        ax0 += w0 * f0.x; ay0 += w0 * f0.y;
        ax1 += w1 * f1.x; ay1 += w1 * f1.y;
    }
    for (; j < e; ++j) {
        int2 m = csr[j];
        float2 f = bf2_to_f2(xbf2[(size_t)m.x * 64 + lane]);
        float wn = __int_as_float(m.y) * di;
        ax0 += wn * f.x; ay0 += wn * f.y;
    }

    float2 acc;
    acc.x = ax0 + ax1;
    acc.y = ay0 + ay1;
    *reinterpret_cast<float2*>(&aggOut[(size_t)wid * 128 + lane * 2]) = acc;
}

// MFMA GEMM, in-place on io: io = relu(io @ W + b), bf16x3, no LDS.
__launch_bounds__(256)
__global__ void gemm_mfma2(const unsigned short* __restrict__ Whi,
                           const unsigned short* __restrict__ Wlo,
                           const float* __restrict__ bias,
                           float* __restrict__ io, int n) {
    const int tid = threadIdx.x;
    const int wv = tid >> 6;
    const int l = tid & 63;
    const int row0 = (blockIdx.x * 4 + wv) * 16;
    if (row0 >= n) return;

    const int arow = row0 + (l & 15);
    const int koff = (l >> 4) * 8;
    const bool rok = arow < n;

    short8v ahi[4], alo[4];
    #pragma unroll
    for (int kc = 0; kc < 4; ++kc) {
        float4 p0 = make_float4(0.f, 0.f, 0.f, 0.f);
        float4 p1 = p0;
        if (rok) {
            const float* src = io + (size_t)arow * 128 + kc * 32 + koff;
            p0 = *reinterpret_cast<const float4*>(src);
            p1 = *reinterpret_cast<const float4*>(src + 4);
        }
        float a8[8] = {p0.x, p0.y, p0.z, p0.w, p1.x, p1.y, p1.z, p1.w};
        #pragma unroll
        for (int j = 0; j < 8; ++j) {
            unsigned short h = bf16_rne(a8[j]);
            ahi[kc][j] = (short)h;
            alo[kc][j] = (short)bf16_rne(a8[j] - bf16f(h));
        }
    }

    const int orow = row0 + (l >> 4) * 4;
    const int cbase = l & 15;
    #pragma unroll
    for (int cf = 0; cf < 8; ++cf) {
        int c = cf * 16 + cbase;
        const unsigned short* ph = Whi + c * 128 + koff;
        const unsigned short* pl = Wlo + c * 128 + koff;
        f32x4 acc = {0.f, 0.f, 0.f, 0.f};
        #pragma unroll
        for (int kc = 0; kc < 4; ++kc) {
            short8v bh = *reinterpret_cast<const short8v*>(ph + kc * 32);
            short8v bl = *reinterpret_cast<const short8v*>(pl + kc * 32);
            acc = __builtin_amdgcn_mfma_f32_16x16x32_bf16(ahi[kc], bh, acc, 0, 0, 0);
            acc = __builtin_amdgcn_mfma_f32_16x16x32_bf16(ahi[kc], bl, acc, 0, 0, 0);
            acc = __builtin_amdgcn_mfma_f32_16x16x32_bf16(alo[kc], bh, acc, 0, 0, 0);
        }
        float bb = bias[c];
        #pragma unroll
        for (int j = 0; j < 4; ++j) {
            int r = orow + j;
            if (r < n) io[(size_t)r * 128 + c] = fmaxf(acc[j] + bb, 0.f);
        }
    }
}

static inline size_t align256(size_t v) { return (v + 255) & ~(size_t)255; }

extern "C" void kernel_launch(void* const* d_in, const int* in_sizes, int n_in,
                              void* d_out, int out_size, void* d_ws, size_t ws_size,
                              hipStream_t stream) {
    const float* x = (const float*)d_in[0];
    const int* ei = (const int*)d_in[1];        // harness: integer -> int32
    const float* w = (const float*)d_in[2];
    const float* W = (const float*)d_in[3];
    const float* b = (const float*)d_in[4];
    float* out = (float*)d_out;

    const int N = in_sizes[0] / 128;
    const int E = in_sizes[2];
    const int* row = ei;       // source
    const int* col = ei + E;   // target

    const int nb = (N + BNODES - 1) / BNODES;   // 1563 coarse buckets
    const int M = nb * NBS;                     // histM elements (~400k)
    const int nScanB = (M + 1023) / 1024;       // 391

    // Workspace (~39.3 MB):
    // [dinv][offs][Whi][Wlo][csr][ UNION: (histM|bsums|bucketed)  vs  xbf2 ]
    char* base = (char*)d_ws;
    size_t off = 0;
    float* dinv = (float*)(base + off);          off = align256(off + (size_t)N * 4);
    int* offs = (int*)(base + off);              off = align256(off + ((size_t)N + 1) * 4);
    unsigned short* Whi = (unsigned short*)(base + off);
    off = align256(off + (size_t)128 * 128 * 2);
    unsigned short* Wlo = (unsigned short*)(base + off);
    off = align256(off + (size_t)128 * 128 * 2);
    int2* csr = (int2*)(base + off);             off = align256(off + (size_t)E * 8);
    // union region
    char* uni = base + off;
    unsigned int* histM = (unsigned int*)uni;                      // M*4 = 1.6 MB
    size_t uoff = align256((size_t)M * 4);
    unsigned int* bsums = (unsigned int*)(uni + uoff);
    uoff = align256(uoff + (size_t)nScanB * 4);
    int2* bucketed = (int2*)(uni + uoff);                          // E*8 = 12.8 MB
    unsigned int* xbf2 = (unsigned int*)uni;                       // N*256 = 25.6 MB

    const int epb = (E + NBS - 1) / NBS;       // 6250
    const int nx8 = (N * 128) / 8;

    // 1: hist (+fused wsplit in the extra block)
    coarse_hist<<<NBS + 1, 1024, nb * 4, stream>>>(col, histM, W, Whi, Wlo, E, epb, nb);
    // 2-3: scan
    scan1i<<<nScanB, 256, 0, stream>>>(histM, bsums, M);
    scan2<<<1, 1024, 0, stream>>>(bsums, nScanB);
    // 4: bucket the edges (zero global atomics)
    bucket_scatter<<<NBS, 1024, 2 * nb * 4, stream>>>(row, col, w, histM, bsums,
                                                      bucketed, E, epb, nb);
    // 5: per-bucket degree + csr placement
    bucket_finalize<<<nb, 256, 0, stream>>>(bucketed, histM, bsums, dinv, offs,
                                            csr, N, E, nb);
    // 6: x*dinv -> bf16 (overwrites union; bucketed is dead)
    cvt_kernel<<<2048, 256, 0, stream>>>(x, dinv, xbf2, nx8);
    // 7: aggregate (R11 loop: 1 dword/lane, 8 rows in flight) -> d_out fp32
    agg_kernel_bf16<<<(N + 3) / 4, 256, 0, stream>>>(xbf2, dinv, offs, csr, out, N);
    // 8: out = relu(out @ W + b), in-place MFMA
    gemm_mfma2<<<(N + 63) / 64, 256, 0, stream>>>(Whi, Wlo, b, out, N);
}